// Round 11
// baseline (84.676 us; speedup 1.0000x reference)
//
#include <hip/hip_runtime.h>
#include <math.h>

#define HW       262144
#define MROWS    100
#define NCOLS    50
#define OUTSZ    (MROWS * NCOLS)
#define NBLK     256               // 1 block/CU; K-chunk = 1024 floats
#define NST      8                 // stages per block, BK = 128 floats

typedef __attribute__((ext_vector_type(8))) _Float16 f16x8;
typedef __attribute__((ext_vector_type(2))) __fp16   fp16x2;
typedef __attribute__((ext_vector_type(4))) float    f32x4;

// LDS buffer: 150 real rows (A 0..99, B 100..149), padded row stride 528 B
// (512 data + 16 pad). Row r base bank = (132r)%32 = (4r)%32 -> 8-way spread,
// fragment reads land 2-way max (free, m136).
// Slots: 33 x 16 B per row, slot = row*33 + c; c==32 re-loads c==31's data
// into the in-row pad (no race). 150*33 = 4950 slots; 20 iters x 256 thr
// = 5120 slots; tail slots 4950..5119 -> bytes 79200..81920 (in-buffer pad).
// BUFBYTES = 5120*16 = 81920; two buffers = 163840 B = full 160 KB LDS.
#define ROWB     528
#define ABROWS   150
#define BUFBYTES 81920

typedef __attribute__((address_space(1))) const unsigned int GU32;
typedef __attribute__((address_space(3))) unsigned int LU32;

// f16 two-term split: hi = RTZ_f16(x), lo = RTZ_f16(x - hi).
__device__ __forceinline__ void split_f16(const float4& v0, const float4& v1,
                                          f16x8& hi, f16x8& lo) {
  float xs[8] = {v0.x, v0.y, v0.z, v0.w, v1.x, v1.y, v1.z, v1.w};
  union { fp16x2 p[4]; f16x8 v; } H, L;
#pragma unroll
  for (int j = 0; j < 4; ++j) {
    H.p[j] = __builtin_amdgcn_cvt_pkrtz(xs[2 * j], xs[2 * j + 1]);
    float l0 = xs[2 * j]     - (float)H.p[j][0];
    float l1 = xs[2 * j + 1] - (float)H.p[j][1];
    L.p[j] = __builtin_amdgcn_cvt_pkrtz(l0, l1);
  }
  hi = H.v; lo = L.v;
}

// ---------------------------------------------------------------------------
// Phase 1: split-K GEMM, LONG-RUN staging. 256 blocks (1/CU), 4 waves (2x2),
// BK=128 fp32 (512 B contiguous per row per stage -> 8 cache lines per
// stream; wave-instr covers 2 streams). global_load_lds staging, ring-2,
// counted vmcnt(20): one full stage in flight under compute.
// ---------------------------------------------------------------------------
__global__ __launch_bounds__(256, 1) void dm_phase1(
    const float* __restrict__ pred, const float* __restrict__ gt,
    float* __restrict__ partial) {
  __shared__ unsigned char smem[2 * BUFBYTES];

  const int b    = blockIdx.x;
  const int tid  = threadIdx.x;
  const int lane = tid & 63;
  const int wid  = tid >> 6;
  const int wi = wid >> 1, wj = wid & 1;
  const int g = lane >> 4, r = lane & 15;

  const int kbase = b << 10;               // 1024 floats per block

  // 20 per-thread staging source pointers (slot -> global addr).
  const float* srcp[20];
#pragma unroll
  for (int it = 0; it < 20; ++it) {
    int s = it * 256 + tid;
    int row = s / 33;                      // compile-time-strength-reduced
    int c   = s - row * 33;
    if (c > 31) c = 31;                    // pad slot dups last 16B chunk
    if (row >= ABROWS) { row = ABROWS - 1; c = 31; }  // tail slots
    const float* base = row < MROWS ? pred + (size_t)row * HW
                                    : gt + (size_t)(row - MROWS) * HW;
    srcp[it] = base + kbase + c * 4;
  }

  auto STAGE = [&](unsigned char* bufb, int s) {   // stage s: +s*128 floats
#pragma unroll
    for (int it = 0; it < 20; ++it)
      __builtin_amdgcn_global_load_lds((GU32*)(srcp[it] + (s << 7)),
          (LU32*)(bufb + (it * 256 + wid * 64) * 16), 16, 0, 0);
  };

  f32x4 acc[4][2] = {};

  auto COMPUTE = [&](const unsigned char* bufb) {
#pragma unroll
    for (int kk = 0; kk < 4; ++kk) {       // 4 x K=32 sub-steps
      f16x8 bh[2], bl[2];
#pragma unroll
      for (int nf = 0; nf < 2; ++nf) {
        int R = wj * 32 + nf * 16 + r;
        if (R > NCOLS - 1) R = NCOLS - 1;  // clamped -> outputs discarded
        const unsigned char* rowb = bufb + (MROWS + R) * ROWB + kk * 128;
        float4 v0 = *(const float4*)(rowb + 32 * g);
        float4 v1 = *(const float4*)(rowb + 32 * g + 16);
        split_f16(v0, v1, bh[nf], bl[nf]);
      }
#pragma unroll
      for (int mf = 0; mf < 4; ++mf) {
        if (wi == 0 || mf < 3) {           // rows 112..127 don't exist
          int R = wi * 64 + mf * 16 + r;
          if (R > MROWS - 1) R = MROWS - 1;
          const unsigned char* rowb = bufb + R * ROWB + kk * 128;
          float4 v0 = *(const float4*)(rowb + 32 * g);
          float4 v1 = *(const float4*)(rowb + 32 * g + 16);
          f16x8 ah, al;
          split_f16(v0, v1, ah, al);
#pragma unroll
          for (int nf = 0; nf < 2; ++nf) {
            acc[mf][nf] = __builtin_amdgcn_mfma_f32_16x16x32_f16(ah, bh[nf], acc[mf][nf], 0, 0, 0);
            acc[mf][nf] = __builtin_amdgcn_mfma_f32_16x16x32_f16(al, bh[nf], acc[mf][nf], 0, 0, 0);
            acc[mf][nf] = __builtin_amdgcn_mfma_f32_16x16x32_f16(ah, bl[nf], acc[mf][nf], 0, 0, 0);
          }
        }
      }
    }
  };

  unsigned char* buf0 = smem;
  unsigned char* buf1 = smem + BUFBYTES;

  STAGE(buf0, 0);
  STAGE(buf1, 1);
  for (int s = 0; s < NST; s += 2) {
    // even half: stage s in buf0 (oldest 20 of 40 outstanding)
    asm volatile("s_waitcnt vmcnt(20)" ::: "memory");
    __builtin_amdgcn_s_barrier();
    COMPUTE(buf0);
    __builtin_amdgcn_s_barrier();          // buf0 free
    if (s + 2 < NST) STAGE(buf0, s + 2);
    // odd half: stage s+1 in buf1
    if (s + 2 < NST) asm volatile("s_waitcnt vmcnt(20)" ::: "memory");
    else             asm volatile("s_waitcnt vmcnt(0)" ::: "memory");
    __builtin_amdgcn_s_barrier();
    COMPUTE(buf1);
    __builtin_amdgcn_s_barrier();          // buf1 free
    if (s + 3 < NST) STAGE(buf1, s + 3);
  }

  // epilogue: C/D layout col = lane&15, row = 4*(lane>>4)+reg
#pragma unroll
  for (int mf = 0; mf < 4; ++mf) {
#pragma unroll
    for (int nf = 0; nf < 2; ++nf) {
#pragma unroll
      for (int qq = 0; qq < 4; ++qq) {
        int row = wi * 64 + mf * 16 + g * 4 + qq;
        int col = wj * 32 + nf * 16 + r;
        if (row < MROWS && col < NCOLS)
          partial[(size_t)b * OUTSZ + row * NCOLS + col] = acc[mf][nf][qq];
      }
    }
  }
}

// ---------------------------------------------------------------------------
// Phase 2a: sum partials over blocks. One wave per 4 consecutive p; all NB/64
// float4 loads issued independently, reduce in double.
// ---------------------------------------------------------------------------
template <int NB>
__global__ void dm_reduce(const float* __restrict__ partial,
                          double* __restrict__ la0) {
  const int tid = threadIdx.x, wid = tid >> 6, lane = tid & 63;
  const int pbase = blockIdx.x * 16 + wid * 4;
  if (pbase >= OUTSZ) return;
  constexpr int IT = NB / 64;
  float4 v[IT];
#pragma unroll
  for (int i = 0; i < IT; ++i)
    v[i] = *(const float4*)(partial + (size_t)(lane + 64 * i) * OUTSZ + pbase);
  double d0 = 0, d1 = 0, d2 = 0, d3 = 0;
#pragma unroll
  for (int i = 0; i < IT; ++i) {
    d0 += (double)v[i].x; d1 += (double)v[i].y;
    d2 += (double)v[i].z; d3 += (double)v[i].w;
  }
#pragma unroll
  for (int off = 32; off; off >>= 1) {
    d0 += __shfl_xor(d0, off);
    d1 += __shfl_xor(d1, off);
    d2 += __shfl_xor(d2, off);
    d3 += __shfl_xor(d3, off);
  }
  if (lane == 0) {
    la0[pbase + 0] = (d0 - 1.0) * 10.0;     // -(1-dot)/0.1
    la0[pbase + 1] = (d1 - 1.0) * 10.0;
    la0[pbase + 2] = (d2 - 1.0) * 10.0;
    la0[pbase + 3] = (d3 - 1.0) * 10.0;
  }
}

// ---------------------------------------------------------------------------
// Phase 2b: Sinkhorn via dual potentials (double), fast __expf on f32 deltas.
// ---------------------------------------------------------------------------
__global__ __launch_bounds__(256) void dm_sinkhorn(const double* __restrict__ la_in,
                                                   float* __restrict__ out) {
  __shared__ double la[OUTSZ];
  __shared__ double rp[MROWS];
  __shared__ double cp[NCOLS];
  const int t = threadIdx.x;
  for (int p = t; p < OUTSZ; p += 256) la[p] = la_in[p];
  if (t < NCOLS) cp[t] = 0.0;
  __syncthreads();
  for (int it = 0; it < 5; ++it) {
    if (t < 2 * MROWS) {                    // rows: 2 lanes per row
      int row = t >> 1, sl = t & 1;
      double m = -1e300;
      for (int j = sl; j < NCOLS; j += 2) m = fmax(m, la[row * NCOLS + j] - cp[j]);
      float s = 0.f;
      for (int j = sl; j < NCOLS; j += 2)
        s += __expf((float)(la[row * NCOLS + j] - cp[j] - m));
      double mo = __shfl_xor(m, 1); float so = __shfl_xor(s, 1);
      double mn = fmax(m, mo);
      s = s * __expf((float)(m - mn)) + so * __expf((float)(mo - mn));
      if (sl == 0) rp[row] = mn + (double)__logf(s);
    }
    __syncthreads();
    if (t < 4 * NCOLS) {                    // cols: 4 lanes per col
      int col = t >> 2, sl = t & 3;
      double m = -1e300;
      for (int i = sl; i < MROWS; i += 4) m = fmax(m, la[i * NCOLS + col] - rp[i]);
      float s = 0.f;
      for (int i = sl; i < MROWS; i += 4)
        s += __expf((float)(la[i * NCOLS + col] - rp[i] - m));
#pragma unroll
      for (int off = 1; off < 4; off <<= 1) {
        double mo = __shfl_xor(m, off); float so = __shfl_xor(s, off);
        double mn = fmax(m, mo);
        s = s * __expf((float)(m - mn)) + so * __expf((float)(mo - mn));
        m = mn;
      }
      if (sl == 0) cp[col] = m + (double)__logf(s);
    }
    __syncthreads();
  }
  for (int p = t; p < OUTSZ; p += 256)
    out[p] = __expf((float)(la[p] - rp[p / NCOLS] - cp[p % NCOLS]));
}

extern "C" void kernel_launch(void* const* d_in, const int* in_sizes, int n_in,
                              void* d_out, int out_size, void* d_ws, size_t ws_size,
                              hipStream_t stream) {
  const float* pred = (const float*)d_in[0];   // [1,100,512,512] fp32
  const float* gt   = (const float*)d_in[1];   // [50,512,512]    fp32
  float* out = (float*)d_out;                  // [1,100,50]      fp32

  float*  partial = (float*)d_ws;
  double* la0 = (double*)((char*)d_ws + (size_t)NBLK * OUTSZ * sizeof(float));

  dm_phase1<<<NBLK, 256, 0, stream>>>(pred, gt, partial);
  dm_reduce<NBLK><<<(OUTSZ + 15) / 16, 256, 0, stream>>>(partial, la0);
  dm_sinkhorn<<<1, 256, 0, stream>>>(la0, out);
}

// Round 13
// 84.350 us; speedup vs baseline: 1.0039x; 1.0039x over previous
//
#include <hip/hip_runtime.h>
#include <math.h>

#define HW       262144
#define MROWS    100
#define NCOLS    50
#define OUTSZ    (MROWS * NCOLS)

typedef __attribute__((ext_vector_type(8))) _Float16 f16x8;
typedef __attribute__((ext_vector_type(2))) __fp16   fp16x2;
typedef __attribute__((ext_vector_type(4))) float    f32x4;

// Per-pair LDS buffer: linear 128 B rows. A rows 0..99 -> [0,12800),
// B rows 0..49 -> [12800,19200), tail pad [19200,20480). 1280 slots x 16 B.
// Ring-2 per pair, 2 pairs: 4 x 20480 = 81920 B -> 2 blocks/CU (exact fit).
// Sources XOR-preswizzled with SOURCE-LOCAL row rr (R12 bug: used global
// LDS row for B -> XOR-4 misplacement); reads unswizzle with R&7 where R is
// the same local row -> both-sides-consistent (rule 21).
#define PBUF     20480
#define ABYTES   12800

typedef __attribute__((address_space(1))) const unsigned int GU32;
typedef __attribute__((address_space(3))) unsigned int LU32;

// f16 two-term split: hi = RTZ_f16(x), lo = RTZ_f16(x - hi).
__device__ __forceinline__ void split_f16(const float4& v0, const float4& v1,
                                          f16x8& hi, f16x8& lo) {
  float xs[8] = {v0.x, v0.y, v0.z, v0.w, v1.x, v1.y, v1.z, v1.w};
  union { fp16x2 p[4]; f16x8 v; } H, L;
#pragma unroll
  for (int j = 0; j < 4; ++j) {
    H.p[j] = __builtin_amdgcn_cvt_pkrtz(xs[2 * j], xs[2 * j + 1]);
    float l0 = xs[2 * j]     - (float)H.p[j][0];
    float l1 = xs[2 * j + 1] - (float)H.p[j][1];
    L.p[j] = __builtin_amdgcn_cvt_pkrtz(l0, l1);
  }
  hi = H.v; lo = L.v;
}

// ---------------------------------------------------------------------------
// Phase 1: split-K GEMM with per-block DUAL independent k-streams.
// Block = 4 waves = 2 wave-pairs. Pair p computes the FULL (112x64-padded)
// 100x50 output over its own k-chunk: pair0 -> chunk b, pair1 -> chunk
// npairs-1-b (different 4-KB channel window: anti-camping).
// BK=32 staging via global_load_lds, ring-2, counted vmcnt(10).
// ---------------------------------------------------------------------------
__global__ __launch_bounds__(256, 2) void dm_phase1(
    const float* __restrict__ pred, const float* __restrict__ gt,
    float* __restrict__ partial, int npairs) {
  __shared__ unsigned char smem[4 * PBUF];

  const int b    = blockIdx.x;
  const int tid  = threadIdx.x;
  const int lane = tid & 63;
  const int wid  = tid >> 6;
  const int p    = wid >> 1;               // wave-pair 0/1
  const int wv   = wid & 1;                // wave within pair
  const int tp   = tid & 127;              // thread within pair
  const int g = lane >> 4, r = lane & 15;

  const int chunkf = HW / npairs;          // floats per stream chunk (pow2)
  const int nst    = chunkf >> 5;          // stages of BK=32
  const int c      = p ? (npairs - 1 - b) : b;
  const int kbase  = c * chunkf;

  // 10 staging source pointers per thread (pair stages its own buffer).
  const float* srcp[10];
#pragma unroll
  for (int it = 0; it < 10; ++it) {
    int s = it * 128 + tp;                 // 0..1279
    int row = s >> 3, t = s & 7;
    const float* base;
    int rr;
    if (row < MROWS)      { rr = row;          base = pred; }
    else if (row < 150)   { rr = row - MROWS;  base = gt;   }
    else                  { rr = NCOLS - 1;    base = gt;   }  // tail slots
    srcp[it] = base + (size_t)rr * HW + kbase + ((t ^ (rr & 7)) << 2);
  }

  unsigned char* pb = smem + p * 2 * PBUF;

  auto STAGE = [&](int q, int s) {
    unsigned char* bufb = pb + q * PBUF;
#pragma unroll
    for (int it = 0; it < 10; ++it)
      __builtin_amdgcn_global_load_lds((GU32*)(srcp[it] + (s << 5)),
          (LU32*)(bufb + (it * 128 + wv * 64) * 16), 16, 0, 0);
  };

  f32x4 acc[4][4] = {};

  auto COMPUTE = [&](int q) {
    const unsigned char* bufb = pb + q * PBUF;
    f16x8 bh[4], bl[4];
#pragma unroll
    for (int nf = 0; nf < 4; ++nf) {
      int R = nf * 16 + r;
      if (R > NCOLS - 1) R = NCOLS - 1;    // clamped cols -> discarded
      const unsigned char* rowb = bufb + ABYTES + R * 128;
      float4 v0 = *(const float4*)(rowb + (((2 * g    ) ^ (R & 7)) << 4));
      float4 v1 = *(const float4*)(rowb + (((2 * g + 1) ^ (R & 7)) << 4));
      split_f16(v0, v1, bh[nf], bl[nf]);
    }
#pragma unroll
    for (int mf = 0; mf < 4; ++mf) {
      if (wv == 0 || mf < 3) {             // rows 112..127 don't exist
        int R = wv * 64 + mf * 16 + r;
        if (R > MROWS - 1) R = MROWS - 1;  // clamped rows -> discarded
        const unsigned char* rowb = bufb + R * 128;
        float4 v0 = *(const float4*)(rowb + (((2 * g    ) ^ (R & 7)) << 4));
        float4 v1 = *(const float4*)(rowb + (((2 * g + 1) ^ (R & 7)) << 4));
        f16x8 ah, al;
        split_f16(v0, v1, ah, al);
#pragma unroll
        for (int nf = 0; nf < 4; ++nf) {
          acc[mf][nf] = __builtin_amdgcn_mfma_f32_16x16x32_f16(ah, bh[nf], acc[mf][nf], 0, 0, 0);
          acc[mf][nf] = __builtin_amdgcn_mfma_f32_16x16x32_f16(al, bh[nf], acc[mf][nf], 0, 0, 0);
          acc[mf][nf] = __builtin_amdgcn_mfma_f32_16x16x32_f16(ah, bl[nf], acc[mf][nf], 0, 0, 0);
        }
      }
    }
  };

  STAGE(0, 0);
  if (nst > 1) STAGE(1, 1);
  for (int s = 0; s < nst; ++s) {
    if (s + 1 < nst) asm volatile("s_waitcnt vmcnt(10)" ::: "memory");
    else             asm volatile("s_waitcnt vmcnt(0)"  ::: "memory");
    __builtin_amdgcn_s_barrier();          // stage-s data landed (both pairs)
    COMPUTE(s & 1);
    __builtin_amdgcn_s_barrier();          // buffer s&1 consumed
    if (s + 2 < nst) STAGE(s & 1, s + 2);
  }

  // epilogue: C/D layout col = lane&15, row = 4*(lane>>4)+reg
  const size_t obase = (size_t)(b * 2 + p) * OUTSZ;
#pragma unroll
  for (int mf = 0; mf < 4; ++mf) {
#pragma unroll
    for (int nf = 0; nf < 4; ++nf) {
#pragma unroll
      for (int qq = 0; qq < 4; ++qq) {
        int row = wv * 64 + mf * 16 + g * 4 + qq;
        int col = nf * 16 + r;
        if (row < MROWS && col < NCOLS)
          partial[obase + row * NCOLS + col] = acc[mf][nf][qq];
      }
    }
  }
}

// ---------------------------------------------------------------------------
// Phase 2a: sum partials over streams. One wave per 4 consecutive p; NB/64
// float4 loads in flight, reduce in double.
// ---------------------------------------------------------------------------
template <int NB>
__global__ void dm_reduce(const float* __restrict__ partial,
                          double* __restrict__ la0) {
  const int tid = threadIdx.x, wid = tid >> 6, lane = tid & 63;
  const int pbase = blockIdx.x * 16 + wid * 4;
  if (pbase >= OUTSZ) return;
  constexpr int IT = NB / 64;
  float4 v[IT];
#pragma unroll
  for (int i = 0; i < IT; ++i)
    v[i] = *(const float4*)(partial + (size_t)(lane + 64 * i) * OUTSZ + pbase);
  double d0 = 0, d1 = 0, d2 = 0, d3 = 0;
#pragma unroll
  for (int i = 0; i < IT; ++i) {
    d0 += (double)v[i].x; d1 += (double)v[i].y;
    d2 += (double)v[i].z; d3 += (double)v[i].w;
  }
#pragma unroll
  for (int off = 32; off; off >>= 1) {
    d0 += __shfl_xor(d0, off);
    d1 += __shfl_xor(d1, off);
    d2 += __shfl_xor(d2, off);
    d3 += __shfl_xor(d3, off);
  }
  if (lane == 0) {
    la0[pbase + 0] = (d0 - 1.0) * 10.0;     // -(1-dot)/0.1
    la0[pbase + 1] = (d1 - 1.0) * 10.0;
    la0[pbase + 2] = (d2 - 1.0) * 10.0;
    la0[pbase + 3] = (d3 - 1.0) * 10.0;
  }
}

// ---------------------------------------------------------------------------
// Phase 2b: Sinkhorn via dual potentials (double), fast __expf on f32 deltas.
// ---------------------------------------------------------------------------
__global__ __launch_bounds__(256) void dm_sinkhorn(const double* __restrict__ la_in,
                                                   float* __restrict__ out) {
  __shared__ double la[OUTSZ];
  __shared__ double rp[MROWS];
  __shared__ double cp[NCOLS];
  const int t = threadIdx.x;
  for (int p = t; p < OUTSZ; p += 256) la[p] = la_in[p];
  if (t < NCOLS) cp[t] = 0.0;
  __syncthreads();
  for (int it = 0; it < 5; ++it) {
    if (t < 2 * MROWS) {                    // rows: 2 lanes per row
      int row = t >> 1, sl = t & 1;
      double m = -1e300;
      for (int j = sl; j < NCOLS; j += 2) m = fmax(m, la[row * NCOLS + j] - cp[j]);
      float s = 0.f;
      for (int j = sl; j < NCOLS; j += 2)
        s += __expf((float)(la[row * NCOLS + j] - cp[j] - m));
      double mo = __shfl_xor(m, 1); float so = __shfl_xor(s, 1);
      double mn = fmax(m, mo);
      s = s * __expf((float)(m - mn)) + so * __expf((float)(mo - mn));
      if (sl == 0) rp[row] = mn + (double)__logf(s);
    }
    __syncthreads();
    if (t < 4 * NCOLS) {                    // cols: 4 lanes per col
      int col = t >> 2, sl = t & 3;
      double m = -1e300;
      for (int i = sl; i < MROWS; i += 4) m = fmax(m, la[i * NCOLS + col] - rp[i]);
      float s = 0.f;
      for (int i = sl; i < MROWS; i += 4)
        s += __expf((float)(la[i * NCOLS + col] - rp[i] - m));
#pragma unroll
      for (int off = 1; off < 4; off <<= 1) {
        double mo = __shfl_xor(m, off); float so = __shfl_xor(s, off);
        double mn = fmax(m, mo);
        s = s * __expf((float)(m - mn)) + so * __expf((float)(mo - mn));
        m = mn;
      }
      if (sl == 0) cp[col] = m + (double)__logf(s);
    }
    __syncthreads();
  }
  for (int p = t; p < OUTSZ; p += 256)
    out[p] = __expf((float)(la[p] - rp[p / NCOLS] - cp[p % NCOLS]));
}

extern "C" void kernel_launch(void* const* d_in, const int* in_sizes, int n_in,
                              void* d_out, int out_size, void* d_ws, size_t ws_size,
                              hipStream_t stream) {
  const float* pred = (const float*)d_in[0];   // [1,100,512,512] fp32
  const float* gt   = (const float*)d_in[1];   // [50,512,512]    fp32
  float* out = (float*)d_out;                  // [1,100,50]      fp32

  auto fits = [&](int np) {
    return ((size_t)np * OUTSZ * sizeof(float) + OUTSZ * sizeof(double)) <= ws_size;
  };
  int npairs = fits(1024) ? 1024 : (fits(512) ? 512 : 256);

  float*  partial = (float*)d_ws;
  double* la0 = (double*)((char*)d_ws + (size_t)npairs * OUTSZ * sizeof(float));

  dm_phase1<<<npairs / 2, 256, 0, stream>>>(pred, gt, partial, npairs);
  if (npairs == 1024)     dm_reduce<1024><<<(OUTSZ + 15) / 16, 256, 0, stream>>>(partial, la0);
  else if (npairs == 512) dm_reduce<512><<<(OUTSZ + 15) / 16, 256, 0, stream>>>(partial, la0);
  else                    dm_reduce<256><<<(OUTSZ + 15) / 16, 256, 0, stream>>>(partial, la0);
  dm_sinkhorn<<<1, 256, 0, stream>>>(la0, out);
}

// Round 14
// 75.989 us; speedup vs baseline: 1.1143x; 1.1100x over previous
//
#include <hip/hip_runtime.h>
#include <math.h>

#define HW       262144
#define MROWS    100
#define NCOLS    50
#define OUTSZ    (MROWS * NCOLS)

typedef __attribute__((ext_vector_type(8))) _Float16 f16x8;
typedef __attribute__((ext_vector_type(2))) __fp16   fp16x2;   // cvt_pkrtz return type
typedef __attribute__((ext_vector_type(4))) float    f32x4;

// LDS buffer (R5-verified): linear 128 B rows. A rows 0..99 -> [0,12800),
// B rows 0..49 -> [12800,19200), pad slots [19200,20480). Ring of 3.
// Sources XOR-preswizzled slot t -> chunk t^(row&7); reads use same XOR.
#define ABYTES   12800
#define BUFBYTES 20480

typedef __attribute__((address_space(1))) const unsigned int GU32;
typedef __attribute__((address_space(3))) unsigned int LU32;

// f16 two-term split: hi = RTZ_f16(x), lo = RTZ_f16(x - hi).
__device__ __forceinline__ void split_f16(const float4& v0, const float4& v1,
                                          f16x8& hi, f16x8& lo) {
  float xs[8] = {v0.x, v0.y, v0.z, v0.w, v1.x, v1.y, v1.z, v1.w};
  union { fp16x2 p[4]; f16x8 v; } H, L;
#pragma unroll
  for (int j = 0; j < 4; ++j) {
    H.p[j] = __builtin_amdgcn_cvt_pkrtz(xs[2 * j], xs[2 * j + 1]);
    float l0 = xs[2 * j]     - (float)H.p[j][0];
    float l1 = xs[2 * j + 1] - (float)H.p[j][1];
    L.p[j] = __builtin_amdgcn_cvt_pkrtz(l0, l1);
  }
  hi = H.v; lo = L.v;
}

// ---------------------------------------------------------------------------
// Phase 1: STRIDED split-K GEMM (the one change vs the R5 66us baseline).
// Block b owns k-chunks {c : c == b mod nblk}, chunk = 32 floats (128 B).
// Stage s reads chunk index (b + nblk*s): per-row run stays 128 B contiguous,
// but the block's physical k-window advances 64 KB per stage (channel
// window hopping), and equal-progress blocks read adjacent 128 B lines.
// Dot products are k-permutation invariant -> correctness unchanged.
// Everything else (ring-3, counted vmcnt(5), XOR swizzle, 2x2 wave grid)
// is byte-identical to R5.
// ---------------------------------------------------------------------------
__global__ __launch_bounds__(256, 2) void dm_phase1(
    const float* __restrict__ pred, const float* __restrict__ gt,
    float* __restrict__ partial, int nblk) {
  __shared__ unsigned char smem[3 * BUFBYTES];

  const int b    = blockIdx.x;
  const int tid  = threadIdx.x;
  const int lane = tid & 63;
  const int wid  = tid >> 6;
  const int wi = wid >> 1, wj = wid & 1;
  const int g = lane >> 4, r = lane & 15;

  const int nst = (HW / 32) / nblk;        // 16 stages for nblk=512

  // per-lane staging source pointers (slot -> xor-preswizzled global addr,
  // chunk base b*32 folded in; stage adds s * nblk * 32 floats)
  const float* srcb[5];
#pragma unroll
  for (int it = 0; it < 5; ++it) {
    int s = it * 256 + tid;              // 0..1279
    const float* p;
    if (s < 800) {                       // A rows 0..99
      int row = s >> 3, t = s & 7;
      p = pred + (size_t)row * HW + b * 32 + ((t ^ (row & 7)) << 2);
    } else if (s < 1200) {               // B rows 0..49
      int s2 = s - 800;
      int row = s2 >> 3, t = s2 & 7;
      p = gt + (size_t)row * HW + b * 32 + ((t ^ (row & 7)) << 2);
    } else {                             // pad slots
      p = pred + ((s - 1200) << 2);
    }
    srcb[it] = p;
  }

  auto STAGE = [&](unsigned char* bufb, int s) {   // stage s: + s*16384 floats
    const int kf = s << 14;                        // nblk(512) * 32
#pragma unroll
    for (int it = 0; it < 5; ++it)
      __builtin_amdgcn_global_load_lds((GU32*)(srcb[it] + kf),
          (LU32*)(bufb + (it * 256 + wid * 64) * 16), 16, 0, 0);
  };

  f32x4 acc[4][2] = {};

  auto COMPUTE = [&](const unsigned char* bufb) {
    f16x8 bh[2], bl[2];
#pragma unroll
    for (int nf = 0; nf < 2; ++nf) {
      int R = wj * 32 + nf * 16 + r;
      if (R > NCOLS - 1) R = NCOLS - 1;  // clamped cols -> outputs discarded
      const unsigned char* rowb = bufb + ABYTES + R * 128;
      float4 v0 = *(const float4*)(rowb + (((2 * g    ) ^ (R & 7)) << 4));
      float4 v1 = *(const float4*)(rowb + (((2 * g + 1) ^ (R & 7)) << 4));
      split_f16(v0, v1, bh[nf], bl[nf]);
    }
#pragma unroll
    for (int mf = 0; mf < 4; ++mf) {
      if (wi == 0 || mf < 3) {           // rows 112..127 don't exist
        int R = wi * 64 + mf * 16 + r;
        if (R > MROWS - 1) R = MROWS - 1; // clamped rows -> outputs discarded
        const unsigned char* rowb = bufb + R * 128;
        float4 v0 = *(const float4*)(rowb + (((2 * g    ) ^ (R & 7)) << 4));
        float4 v1 = *(const float4*)(rowb + (((2 * g + 1) ^ (R & 7)) << 4));
        f16x8 ah, al;
        split_f16(v0, v1, ah, al);
#pragma unroll
        for (int nf = 0; nf < 2; ++nf) {
          acc[mf][nf] = __builtin_amdgcn_mfma_f32_16x16x32_f16(ah, bh[nf], acc[mf][nf], 0, 0, 0);
          acc[mf][nf] = __builtin_amdgcn_mfma_f32_16x16x32_f16(al, bh[nf], acc[mf][nf], 0, 0, 0);
          acc[mf][nf] = __builtin_amdgcn_mfma_f32_16x16x32_f16(ah, bl[nf], acc[mf][nf], 0, 0, 0);
        }
      }
    }
  };

  // prologue: 2 stages in flight
  STAGE(smem, 0);
  if (nst > 1) STAGE(smem + BUFBYTES, 1);

  int qc = 0;                            // ring index of buffer being computed
  for (int s = 0; s < nst; ++s) {
    if (s + 1 < nst) asm volatile("s_waitcnt vmcnt(5)" ::: "memory");
    else             asm volatile("s_waitcnt vmcnt(0)" ::: "memory");
    __builtin_amdgcn_s_barrier();        // all waves' stage-s loads landed
    COMPUTE(smem + qc * BUFBYTES);
    if (s + 2 < nst) {
      int qs = qc + 2; if (qs >= 3) qs -= 3;
      STAGE(smem + qs * BUFBYTES, s + 2);
    }
    qc = (qc == 2) ? 0 : qc + 1;
  }

  // epilogue: C/D layout col = lane&15, row = 4*(lane>>4)+reg
#pragma unroll
  for (int mf = 0; mf < 4; ++mf) {
#pragma unroll
    for (int nf = 0; nf < 2; ++nf) {
#pragma unroll
      for (int qq = 0; qq < 4; ++qq) {
        int row = wi * 64 + mf * 16 + g * 4 + qq;
        int col = wj * 32 + nf * 16 + r;
        if (row < MROWS && col < NCOLS)
          partial[(size_t)b * OUTSZ + row * NCOLS + col] = acc[mf][nf][qq];
      }
    }
  }
}

// ---------------------------------------------------------------------------
// Phase 2a: sum partials over blocks. One wave per 4 consecutive p; NB/64
// float4 loads in flight, reduce in double.
// ---------------------------------------------------------------------------
template <int NB>
__global__ void dm_reduce(const float* __restrict__ partial,
                          double* __restrict__ la0) {
  const int tid = threadIdx.x, wid = tid >> 6, lane = tid & 63;
  const int pbase = blockIdx.x * 16 + wid * 4;
  if (pbase >= OUTSZ) return;
  constexpr int IT = NB / 64;
  float4 v[IT];
#pragma unroll
  for (int i = 0; i < IT; ++i)
    v[i] = *(const float4*)(partial + (size_t)(lane + 64 * i) * OUTSZ + pbase);
  double d0 = 0, d1 = 0, d2 = 0, d3 = 0;
#pragma unroll
  for (int i = 0; i < IT; ++i) {
    d0 += (double)v[i].x; d1 += (double)v[i].y;
    d2 += (double)v[i].z; d3 += (double)v[i].w;
  }
#pragma unroll
  for (int off = 32; off; off >>= 1) {
    d0 += __shfl_xor(d0, off);
    d1 += __shfl_xor(d1, off);
    d2 += __shfl_xor(d2, off);
    d3 += __shfl_xor(d3, off);
  }
  if (lane == 0) {
    la0[pbase + 0] = (d0 - 1.0) * 10.0;   // -(1-dot)/0.1
    la0[pbase + 1] = (d1 - 1.0) * 10.0;
    la0[pbase + 2] = (d2 - 1.0) * 10.0;
    la0[pbase + 3] = (d3 - 1.0) * 10.0;
  }
}

// ---------------------------------------------------------------------------
// Phase 2b: Sinkhorn via dual potentials (double), fast __expf on f32 deltas.
// ---------------------------------------------------------------------------
__global__ __launch_bounds__(256) void dm_sinkhorn(const double* __restrict__ la_in,
                                                   float* __restrict__ out) {
  __shared__ double la[OUTSZ];
  __shared__ double rp[MROWS];
  __shared__ double cp[NCOLS];
  const int t = threadIdx.x;
  for (int p = t; p < OUTSZ; p += 256) la[p] = la_in[p];
  if (t < NCOLS) cp[t] = 0.0;
  __syncthreads();
  for (int it = 0; it < 5; ++it) {
    if (t < 2 * MROWS) {                  // rows: 2 lanes per row
      int row = t >> 1, sl = t & 1;
      double m = -1e300;
      for (int j = sl; j < NCOLS; j += 2) m = fmax(m, la[row * NCOLS + j] - cp[j]);
      float s = 0.f;
      for (int j = sl; j < NCOLS; j += 2)
        s += __expf((float)(la[row * NCOLS + j] - cp[j] - m));
      double mo = __shfl_xor(m, 1); float so = __shfl_xor(s, 1);
      double mn = fmax(m, mo);
      s = s * __expf((float)(m - mn)) + so * __expf((float)(mo - mn));
      if (sl == 0) rp[row] = mn + (double)__logf(s);
    }
    __syncthreads();
    if (t < 4 * NCOLS) {                  // cols: 4 lanes per col
      int col = t >> 2, sl = t & 3;
      double m = -1e300;
      for (int i = sl; i < MROWS; i += 4) m = fmax(m, la[i * NCOLS + col] - rp[i]);
      float s = 0.f;
      for (int i = sl; i < MROWS; i += 4)
        s += __expf((float)(la[i * NCOLS + col] - rp[i] - m));
#pragma unroll
      for (int off = 1; off < 4; off <<= 1) {
        double mo = __shfl_xor(m, off); float so = __shfl_xor(s, off);
        double mn = fmax(m, mo);
        s = s * __expf((float)(m - mn)) + so * __expf((float)(mo - mn));
        m = mn;
      }
      if (sl == 0) cp[col] = m + (double)__logf(s);
    }
    __syncthreads();
  }
  for (int p = t; p < OUTSZ; p += 256)
    out[p] = __expf((float)(la[p] - rp[p / NCOLS] - cp[p % NCOLS]));
}

extern "C" void kernel_launch(void* const* d_in, const int* in_sizes, int n_in,
                              void* d_out, int out_size, void* d_ws, size_t ws_size,
                              hipStream_t stream) {
  const float* pred = (const float*)d_in[0];   // [1,100,512,512] fp32
  const float* gt   = (const float*)d_in[1];   // [50,512,512]    fp32
  float* out = (float*)d_out;                  // [1,100,50]      fp32

  auto fits = [&](int nb) {
    return ((size_t)nb * OUTSZ * sizeof(float) + OUTSZ * sizeof(double)) <= ws_size;
  };
  int nblk = fits(512) ? 512 : 256;

  float*  partial = (float*)d_ws;
  double* la0 = (double*)((char*)d_ws + (size_t)nblk * OUTSZ * sizeof(float));

  dm_phase1<<<nblk, 256, 0, stream>>>(pred, gt, partial, nblk);
  if (nblk == 512) dm_reduce<512><<<(OUTSZ + 15) / 16, 256, 0, stream>>>(partial, la0);
  else             dm_reduce<256><<<(OUTSZ + 15) / 16, 256, 0, stream>>>(partial, la0);
  dm_sinkhorn<<<1, 256, 0, stream>>>(la0, out);
}